// Round 7
// baseline (464.847 us; speedup 1.0000x reference)
//
#include <hip/hip_runtime.h>
#include <math.h>

#define NRES 512
#define CSD  384
#define CZD  128

// workspace layout (float offsets)
#define OFF_Q     0         //  512*192
#define OFF_KT    98304     //  192*512   kkT[c][k]
#define OFF_VC    196608    //  512*512   vcomb[k][u]  (u<192: v, 192..479: v_pts)
#define OFF_QP    458752    //  512*144   q_pts row-major
#define OFF_KPT   532480    //  144*512   kptsT[dim][k]
#define OFF_A     606208    //  scratch region (praw / part aliases)
#define OFF_OCAT  3751936   //  512*2112
#define OFF_WCAT  4833280   //  384*1152 wcat + 1152 bcat
#define OFF_BCAT  (OFF_WCAT + 442368)
// aliases inside OFF_A region (disjoint lifetimes):
#define OFF_PRAWQ OFF_A            // 512*144 (k_proj2 -> k_rot)
#define OFF_PRAWK (OFF_A + 73728)  // 512*432
#define OFF_PART  OFF_A            // 6*196608 (k_out2 -> k_red)

// ---------------------------------------------------------------- weight concat
__global__ __launch_bounds__(256) void k_wcat(
    const float* __restrict__ w_q, const float* __restrict__ b_q,
    const float* __restrict__ w_kv, const float* __restrict__ b_kv,
    const float* __restrict__ w_qp, const float* __restrict__ b_qp,
    const float* __restrict__ w_kvp, const float* __restrict__ b_kvp,
    float* __restrict__ wcat, float* __restrict__ bcat)
{
    const int idx = blockIdx.x * 256 + threadIdx.x;
    if (idx < 442368) {
        const int k = idx / 1152, c = idx % 1152;
        float v;
        if (c < 192)      v = w_q[k*192 + c];
        else if (c < 576) v = w_kv[k*384 + (c - 192)];
        else if (c < 720) v = w_qp[k*144 + (c - 576)];
        else              v = w_kvp[k*432 + (c - 720)];
        wcat[idx] = v;
    } else if (idx < 443520) {
        const int c = idx - 442368;
        float v;
        if (c < 192)      v = b_q[c];
        else if (c < 576) v = b_kv[c - 192];
        else if (c < 720) v = b_qp[c - 576];
        else              v = b_kvp[c - 720];
        bcat[c] = v;
    }
}

// ---------------------------------------------------------------- projections GEMM
__global__ __launch_bounds__(256) void k_proj2(
    const float* __restrict__ s, const float* __restrict__ wcat, const float* __restrict__ bcat,
    float* __restrict__ q, float* __restrict__ kkT, float* __restrict__ vcomb,
    float* __restrict__ praw_q, float* __restrict__ praw_kv)
{
    const int ct = blockIdx.x;
    const int n0 = blockIdx.y * 32;
    const int t = threadIdx.x;

    __shared__ float sT[32][34];
    __shared__ float wt[32][36];

    const int lr = t >> 3, lc4 = t & 7;
    const int tr = t >> 4, tc = t & 15;
    float4 sv4, wv4;

    sv4 = *(const float4*)&s[(n0 + lr) * CSD + lc4 * 4];
    wv4 = *(const float4*)&wcat[lr * 1152 + ct * 32 + lc4 * 4];
    sT[lc4*4+0][lr] = sv4.x; sT[lc4*4+1][lr] = sv4.y; sT[lc4*4+2][lr] = sv4.z; sT[lc4*4+3][lr] = sv4.w;
    *(float4*)&wt[lr][lc4*4] = wv4;
    __syncthreads();

    float a00 = 0.f, a01 = 0.f, a10 = 0.f, a11 = 0.f;

    for (int it = 0; it < 12; ++it) {
        if (it < 11) {
            const int k0 = (it + 1) * 32;
            sv4 = *(const float4*)&s[(n0 + lr) * CSD + k0 + lc4 * 4];
            wv4 = *(const float4*)&wcat[(k0 + lr) * 1152 + ct * 32 + lc4 * 4];
        }
        #pragma unroll
        for (int kx = 0; kx < 32; ++kx) {
            float2 ss = *(const float2*)&sT[kx][tr * 2];
            float2 ww = *(const float2*)&wt[kx][tc * 2];
            a00 += ss.x * ww.x; a01 += ss.x * ww.y;
            a10 += ss.y * ww.x; a11 += ss.y * ww.y;
        }
        __syncthreads();
        if (it < 11) {
            sT[lc4*4+0][lr] = sv4.x; sT[lc4*4+1][lr] = sv4.y; sT[lc4*4+2][lr] = sv4.z; sT[lc4*4+3][lr] = sv4.w;
            *(float4*)&wt[lr][lc4*4] = wv4;
            __syncthreads();
        }
    }

    float accv[2][2] = {{a00, a01}, {a10, a11}};
    #pragma unroll
    for (int i = 0; i < 2; ++i) {
        const int n = n0 + tr * 2 + i;
        #pragma unroll
        for (int j = 0; j < 2; ++j) {
            const int gcol = ct * 32 + tc * 2 + j;
            const float v = accv[i][j] + bcat[gcol];
            if (gcol < 192) {
                q[n*192 + gcol] = v;
            } else if (gcol < 576) {
                int g = gcol - 192, h = g >> 5, cc = g & 31;
                if (cc < 16) kkT[(h*16 + cc)*NRES + n] = v;
                else         vcomb[n*NRES + h*16 + (cc-16)] = v;
            } else if (gcol < 720) {
                praw_q[n*144 + (gcol - 576)] = v;
            } else {
                praw_kv[n*432 + (gcol - 720)] = v;
            }
        }
    }
}

// ---------------------------------------------------------------- rigid-frame rotation
__global__ __launch_bounds__(256) void k_rot(
    const float* __restrict__ praw_q, const float* __restrict__ praw_kv,
    const float* __restrict__ rot, const float* __restrict__ trans,
    float* __restrict__ q_pts, float* __restrict__ kptsT, float* __restrict__ vcomb)
{
    const int idx = blockIdx.x * 256 + threadIdx.x;
    const int n = idx / 192, u = idx % 192;
    const float* R = rot + n*9;
    const float* T = trans + n*3;
    float px, py, pz;
    if (u < 48) {
        px = praw_q[n*144 + u]; py = praw_q[n*144 + 48 + u]; pz = praw_q[n*144 + 96 + u];
    } else {
        int pt = u - 48;
        px = praw_kv[n*432 + pt]; py = praw_kv[n*432 + 144 + pt]; pz = praw_kv[n*432 + 288 + pt];
    }
    float x  = R[0]*px + R[1]*py + R[2]*pz + T[0];
    float y  = R[3]*px + R[4]*py + R[5]*pz + T[1];
    float zc = R[6]*px + R[7]*py + R[8]*pz + T[2];
    if (u < 48) {
        int o = (n*48 + u)*3;
        q_pts[o] = x; q_pts[o+1] = y; q_pts[o+2] = zc;
    } else {
        int pt = u - 48;
        int h = pt / 12, pp = pt % 12;
        if (pp < 4) {
            int dim = (h*4 + pp)*3;
            kptsT[(dim+0)*NRES + n] = x;
            kptsT[(dim+1)*NRES + n] = y;
            kptsT[(dim+2)*NRES + n] = zc;
        } else {
            int u2 = (h*8 + (pp-4))*3;
            vcomb[n*NRES + 192 + u2+0] = x;
            vcomb[n*NRES + 192 + u2+1] = y;
            vcomb[n*NRES + 192 + u2+2] = zc;
        }
    }
}

// ---------------------------------------------------------------- one-pass flash-style fused row kernel
// per block: q-row qn. k tiled 8x64. z read ONCE from HBM (reg-prefetch double buffer).
// online softmax: wave w owns heads 3w..3w+2 (running m,s in regs; per-tile rescale factor via LDS).
__global__ __launch_bounds__(256) void k_row2(
    const float* __restrict__ z,
    const float* __restrict__ q, const float* __restrict__ kkT, const float* __restrict__ vcomb,
    const float* __restrict__ q_pts, const float* __restrict__ kptsT,
    const float* __restrict__ w_b, const float* __restrict__ b_b,
    const float* __restrict__ head_weights, const float* __restrict__ mask,
    const float* __restrict__ rot, const float* __restrict__ trans,
    float* __restrict__ o_cat)
{
    const int qn = blockIdx.x;
    const int t = threadIdx.x;

    __shared__ float zt[64][132];        // z tile, float4-aligned rows; aliased as o_pair reduce buffer at the end
    __shared__ float wb[1536];
    __shared__ float part[4][64][13];    // bias partials
    __shared__ float bt[12][64];         // bias for tile
    __shared__ float pt[12][66];         // p (unnormalized softmax) for tile
    __shared__ float fs[12];             // per-tile rescale factor
    __shared__ float ss[12];             // final softmax denominators
    __shared__ float q_lds[192];
    __shared__ float qp_lds[144];
    __shared__ float hw_lds[12];
    __shared__ float optraw[288];

    for (int i = t; i < 1536; i += 256) wb[i] = w_b[i];
    if (t < 192) q_lds[t] = q[qn*192 + t];
    if (t < 144) qp_lds[t] = q_pts[qn*144 + t];
    if (t < 12)  hw_lds[t] = logf(1.f + expf(head_weights[t])) * 0.13608276f;
    const float mq = mask[qn];

    const int kx = t & 63, hgrp = t >> 6;   // logits/bias layout (wave hgrp owns heads 3*hgrp..+2)
    const int c4 = t & 31, kgrp = t >> 5;   // o_pair layout

    float m_run0 = -1e30f, m_run1 = -1e30f, m_run2 = -1e30f;
    float s_run0 = 0.f, s_run1 = 0.f, s_run2 = 0.f;
    float4 opa[12];
    #pragma unroll
    for (int h = 0; h < 12; ++h) opa[h] = make_float4(0.f, 0.f, 0.f, 0.f);
    float oacc0 = 0.f, oacc1 = 0.f;
    const int u0 = t;
    const int h0 = (u0 < 192) ? (u0 >> 4) : (u0 - 192) / 24;
    const int u1 = t + 256;
    const bool has_u1 = (u1 < 480);
    const int h1 = has_u1 ? (u1 - 192) / 24 : 0;

    // prologue: stage tile 0
    float4 stg[8];
    {
        const float4* zp = (const float4*)(z + (size_t)qn * NRES * CZD);
        #pragma unroll
        for (int j = 0; j < 8; ++j) stg[j] = zp[t + j*256];
        #pragma unroll
        for (int j = 0; j < 8; ++j) {
            int idx = t + j*256;
            *(float4*)&zt[idx >> 5][(idx & 31) * 4] = stg[j];
        }
    }
    __syncthreads();

    for (int kt = 0; kt < 8; ++kt) {
        const int k0 = kt * 64;

        // issue next-tile global loads (latency hides under this tile's compute)
        if (kt < 7) {
            const float4* zp = (const float4*)(z + ((size_t)qn * NRES + k0 + 64) * CZD);
            #pragma unroll
            for (int j = 0; j < 8; ++j) stg[j] = zp[t + j*256];
        }

        // ---- bias for tile: thread (kx, qr=hgrp) handles 32 c's
        {
            float acc[12];
            #pragma unroll
            for (int h = 0; h < 12; ++h) acc[h] = 0.f;
            #pragma unroll
            for (int cc = 0; cc < 8; ++cc) {
                float4 zv = *(const float4*)&zt[kx][hgrp*32 + cc*4];
                const float* wp = &wb[(hgrp*32 + cc*4) * 12];
                #pragma unroll
                for (int h = 0; h < 12; ++h) acc[h] += zv.x * wp[h];
                #pragma unroll
                for (int h = 0; h < 12; ++h) acc[h] += zv.y * wp[12 + h];
                #pragma unroll
                for (int h = 0; h < 12; ++h) acc[h] += zv.z * wp[24 + h];
                #pragma unroll
                for (int h = 0; h < 12; ++h) acc[h] += zv.w * wp[36 + h];
            }
            #pragma unroll
            for (int h = 0; h < 12; ++h) part[hgrp][kx][h] = acc[h];
        }
        __syncthreads();
        for (int d = t; d < 768; d += 256) {
            int h = d >> 6, k2 = d & 63;
            bt[h][k2] = b_b[h] + part[0][k2][h] + part[1][k2][h] + part[2][k2][h] + part[3][k2][h];
        }
        __syncthreads();

        // ---- logits + online softmax update
        {
            const float mk = (mq * mask[k0 + kx] - 1.f) * 100000.f;
            #pragma unroll
            for (int hh = 0; hh < 3; ++hh) {
                const int h = hgrp*3 + hh;
                float acc = 0.f;
                const float* kT = kkT + (h*16)*NRES + k0 + kx;
                #pragma unroll
                for (int c = 0; c < 16; ++c) acc += q_lds[h*16 + c] * kT[c*NRES];
                acc *= 0.14433757f;
                acc += 0.57735027f * bt[h][kx];
                float dsum = 0.f;
                const float* kpT = kptsT + (h*12)*NRES + k0 + kx;
                #pragma unroll
                for (int d = 0; d < 12; ++d) { float df = qp_lds[h*12 + d] - kpT[d*NRES]; dsum += df*df; }
                float l = acc - 0.5f * hw_lds[h] * dsum + mk;

                float m_old = (hh == 0) ? m_run0 : (hh == 1) ? m_run1 : m_run2;
                float s_old = (hh == 0) ? s_run0 : (hh == 1) ? s_run1 : s_run2;
                float pm = l;
                #pragma unroll
                for (int off = 32; off > 0; off >>= 1) pm = fmaxf(pm, __shfl_xor(pm, off));
                float mnew = fmaxf(m_old, pm);
                float f = __expf(m_old - mnew);
                float p = __expf(l - mnew);
                float psum = p;
                #pragma unroll
                for (int off = 32; off > 0; off >>= 1) psum += __shfl_xor(psum, off);
                float snew = s_old * f + psum;
                if (hh == 0) { m_run0 = mnew; s_run0 = snew; }
                else if (hh == 1) { m_run1 = mnew; s_run1 = snew; }
                else { m_run2 = mnew; s_run2 = snew; }
                pt[h][kx] = p;
                if (kx == 0) fs[h] = f;
            }
        }
        __syncthreads();

        // ---- accumulate: o_pair from LDS z tile; o/o_pt from vcomb (L2)
        {
            #pragma unroll
            for (int h = 0; h < 12; ++h) {
                const float f = fs[h];
                opa[h].x *= f; opa[h].y *= f; opa[h].z *= f; opa[h].w *= f;
            }
            #pragma unroll
            for (int j = 0; j < 8; ++j) {
                const int k = kgrp*8 + j;
                float4 zv = *(const float4*)&zt[k][c4*4];
                #pragma unroll
                for (int h = 0; h < 12; ++h) {
                    float pv = pt[h][k];
                    opa[h].x += pv*zv.x; opa[h].y += pv*zv.y;
                    opa[h].z += pv*zv.z; opa[h].w += pv*zv.w;
                }
            }
            oacc0 *= fs[h0];
            if (has_u1) oacc1 *= fs[h1];
            const float* vb = vcomb + (size_t)k0 * NRES;
            #pragma unroll 4
            for (int k = 0; k < 64; ++k) {
                const float* vrow = vb + (size_t)k * NRES;
                oacc0 += pt[h0][k] * vrow[u0];
                if (has_u1) oacc1 += pt[h1][k] * vrow[u1];
            }
        }
        __syncthreads();

        // ---- commit prefetched tile to LDS
        if (kt < 7) {
            #pragma unroll
            for (int j = 0; j < 8; ++j) {
                int idx = t + j*256;
                *(float4*)&zt[idx >> 5][(idx & 31) * 4] = stg[j];
            }
            __syncthreads();
        }
    }

    // ---- finalize softmax denominators
    if (kx == 0) {
        ss[hgrp*3 + 0] = s_run0;
        ss[hgrp*3 + 1] = s_run1;
        ss[hgrp*3 + 2] = s_run2;
    }
    __syncthreads();

    // ---- o_pair: reduce kgrp pairs, stage, final sum (zt dead -> reuse as reduce buffer)
    {
        #pragma unroll
        for (int h = 0; h < 12; ++h) {
            opa[h].x += __shfl_xor(opa[h].x, 32);
            opa[h].y += __shfl_xor(opa[h].y, 32);
            opa[h].z += __shfl_xor(opa[h].z, 32);
            opa[h].w += __shfl_xor(opa[h].w, 32);
        }
        float (*pred)[12][128] = (float (*)[12][128])zt;
        const int wave = t >> 6;
        if ((t & 63) < 32) {
            #pragma unroll
            for (int h = 0; h < 12; ++h) {
                pred[wave][h][c4*4+0] = opa[h].x;
                pred[wave][h][c4*4+1] = opa[h].y;
                pred[wave][h][c4*4+2] = opa[h].z;
                pred[wave][h][c4*4+3] = opa[h].w;
            }
        }
        __syncthreads();
        for (int i = t; i < 1536; i += 256) {
            int h = i >> 7, c = i & 127;
            float v = (pred[0][h][c] + pred[1][h][c] + pred[2][h][c] + pred[3][h][c]) / ss[h];
            o_cat[qn*2112 + 576 + h*128 + c] = v;
        }
    }

    // ---- o / o_pt normalize
    {
        float v0 = oacc0 / ss[h0];
        if (u0 < 192) o_cat[qn*2112 + u0] = v0;
        else          optraw[u0 - 192] = v0;
        if (has_u1)   optraw[u1 - 192] = oacc1 / ss[h1];
    }
    __syncthreads();

    // ---- inverse rotation + norms
    if (t < 96) {
        const float* R = rot + qn*9;
        const float* T = trans + qn*3;
        float ox = optraw[t*3]   - T[0];
        float oy = optraw[t*3+1] - T[1];
        float oz = optraw[t*3+2] - T[2];
        float x  = R[0]*ox + R[3]*oy + R[6]*oz;
        float y  = R[1]*ox + R[4]*oy + R[7]*oz;
        float zc = R[2]*ox + R[5]*oy + R[8]*oz;
        float* ob = o_cat + qn*2112;
        ob[192 + t] = x;
        ob[288 + t] = y;
        ob[384 + t] = zc;
        ob[480 + t] = sqrtf(x*x + y*y + zc*zc + 1e-8f);
    }
}

// ---------------------------------------------------------------- final GEMM
__global__ __launch_bounds__(256) void k_out2(
    const float* __restrict__ o_cat, const float* __restrict__ w_out, float* __restrict__ part)
{
    const int ct = blockIdx.x;
    const int n0 = blockIdx.y * 32;
    const int kc = blockIdx.z;
    const int t = threadIdx.x;

    __shared__ float oT[32][34];
    __shared__ float wt[32][36];

    const int lr = t >> 3, lc4 = t & 7;
    const int tr = t >> 4, tc = t & 15;
    const int kbase = kc * 352;
    float4 ov4, wv4;

    ov4 = *(const float4*)&o_cat[(n0 + lr) * 2112 + kbase + lc4 * 4];
    wv4 = *(const float4*)&w_out[(kbase + lr) * 384 + ct * 32 + lc4 * 4];
    oT[lc4*4+0][lr] = ov4.x; oT[lc4*4+1][lr] = ov4.y; oT[lc4*4+2][lr] = ov4.z; oT[lc4*4+3][lr] = ov4.w;
    *(float4*)&wt[lr][lc4*4] = wv4;
    __syncthreads();

    float a00 = 0.f, a01 = 0.f, a10 = 0.f, a11 = 0.f;

    for (int it = 0; it < 11; ++it) {
        if (it < 10) {
            const int k0 = kbase + (it + 1) * 32;
            ov4 = *(const float4*)&o_cat[(n0 + lr) * 2112 + k0 + lc4 * 4];
            wv4 = *(const float4*)&w_out[(k0 + lr) * 384 + ct * 32 + lc4 * 4];
        }
        #pragma unroll
        for (int kx = 0; kx < 32; ++kx) {
            float2 oo = *(const float2*)&oT[kx][tr * 2];
            float2 ww = *(const float2*)&wt[kx][tc * 2];
            a00 += oo.x * ww.x; a01 += oo.x * ww.y;
            a10 += oo.y * ww.x; a11 += oo.y * ww.y;
        }
        __syncthreads();
        if (it < 10) {
            oT[lc4*4+0][lr] = ov4.x; oT[lc4*4+1][lr] = ov4.y; oT[lc4*4+2][lr] = ov4.z; oT[lc4*4+3][lr] = ov4.w;
            *(float4*)&wt[lr][lc4*4] = wv4;
            __syncthreads();
        }
    }

    float* pp = part + (size_t)kc * 196608;
    pp[(n0 + tr*2 + 0)*384 + ct*32 + tc*2 + 0] = a00;
    pp[(n0 + tr*2 + 0)*384 + ct*32 + tc*2 + 1] = a01;
    pp[(n0 + tr*2 + 1)*384 + ct*32 + tc*2 + 0] = a10;
    pp[(n0 + tr*2 + 1)*384 + ct*32 + tc*2 + 1] = a11;
}

__global__ __launch_bounds__(256) void k_red(
    const float* __restrict__ part, const float* __restrict__ b_out, float* __restrict__ out)
{
    const int i = blockIdx.x*256 + threadIdx.x;
    float acc = b_out[i % 384];
    #pragma unroll
    for (int dc = 0; dc < 6; ++dc) acc += part[(size_t)dc*196608 + i];
    out[i] = acc;
}

// ----------------------------------------------------------------
extern "C" void kernel_launch(void* const* d_in, const int* in_sizes, int n_in,
                              void* d_out, int out_size, void* d_ws, size_t ws_size,
                              hipStream_t stream) {
    (void)in_sizes; (void)n_in; (void)out_size; (void)ws_size;
    const float* s      = (const float*)d_in[0];
    const float* z      = (const float*)d_in[1];
    const float* rot    = (const float*)d_in[2];
    const float* trans  = (const float*)d_in[3];
    const float* mask   = (const float*)d_in[4];
    const float* w_q    = (const float*)d_in[5];
    const float* b_q    = (const float*)d_in[6];
    const float* w_kv   = (const float*)d_in[7];
    const float* b_kv   = (const float*)d_in[8];
    const float* w_qp   = (const float*)d_in[9];
    const float* b_qp   = (const float*)d_in[10];
    const float* w_kvp  = (const float*)d_in[11];
    const float* b_kvp  = (const float*)d_in[12];
    const float* w_b    = (const float*)d_in[13];
    const float* b_b    = (const float*)d_in[14];
    const float* hwts   = (const float*)d_in[15];
    const float* w_out  = (const float*)d_in[16];
    const float* b_out  = (const float*)d_in[17];
    float* out = (float*)d_out;
    float* ws  = (float*)d_ws;

    float* q      = ws + OFF_Q;
    float* kkT    = ws + OFF_KT;
    float* vcomb  = ws + OFF_VC;
    float* qp     = ws + OFF_QP;
    float* kptsT  = ws + OFF_KPT;
    float* ocat   = ws + OFF_OCAT;
    float* wcat   = ws + OFF_WCAT;
    float* bcat   = ws + OFF_BCAT;
    float* part   = ws + OFF_PART;
    float* praw_q  = ws + OFF_PRAWQ;
    float* praw_kv = ws + OFF_PRAWK;

    k_wcat<<<dim3(1733), dim3(256), 0, stream>>>(w_q, b_q, w_kv, b_kv, w_qp, b_qp, w_kvp, b_kvp, wcat, bcat);
    k_proj2<<<dim3(36, 16), dim3(256), 0, stream>>>(s, wcat, bcat, q, kkT, vcomb, praw_q, praw_kv);
    k_rot<<<dim3(384), dim3(256), 0, stream>>>(praw_q, praw_kv, rot, trans, qp, kptsT, vcomb);
    k_row2<<<dim3(NRES), dim3(256), 0, stream>>>(z, q, kkT, vcomb, qp, kptsT,
        w_b, b_b, hwts, mask, rot, trans, ocat);
    k_out2<<<dim3(12, 16, 6), dim3(256), 0, stream>>>(ocat, w_out, part);
    k_red<<<dim3(768), dim3(256), 0, stream>>>(part, b_out, out);
}

// Round 8
// 235.278 us; speedup vs baseline: 1.9757x; 1.9757x over previous
//
#include <hip/hip_runtime.h>
#include <math.h>

#define NRES 512
#define CSD  384
#define CZD  128

// workspace layout (float offsets)
#define OFF_Q     0         //  512*192
#define OFF_KT    98304     //  192*512   kkT[c][k]
#define OFF_VC    196608    //  512*512   vcomb[k][u]  (u<192: v, 192..479: v_pts)
#define OFF_QP    458752    //  512*144   q_pts row-major
#define OFF_KPT   532480    //  144*512   kptsT[dim][k]
#define OFF_A     606208    //  scratch region (praw / part aliases)
#define OFF_OCAT  3751936   //  512*2112
#define OFF_WCAT  4833280   //  384*1152 wcat + 1152 bcat
#define OFF_BCAT  (OFF_WCAT + 442368)
// aliases inside OFF_A region (disjoint lifetimes):
#define OFF_PRAWQ OFF_A            // 512*144 (k_proj2 -> k_rot)
#define OFF_PRAWK (OFF_A + 73728)  // 512*432
#define OFF_PART  OFF_A            // 6*196608 (k_out2 -> k_red)

// ---------------------------------------------------------------- weight concat
__global__ __launch_bounds__(256) void k_wcat(
    const float* __restrict__ w_q, const float* __restrict__ b_q,
    const float* __restrict__ w_kv, const float* __restrict__ b_kv,
    const float* __restrict__ w_qp, const float* __restrict__ b_qp,
    const float* __restrict__ w_kvp, const float* __restrict__ b_kvp,
    float* __restrict__ wcat, float* __restrict__ bcat)
{
    const int idx = blockIdx.x * 256 + threadIdx.x;
    if (idx < 442368) {
        const int k = idx / 1152, c = idx % 1152;
        float v;
        if (c < 192)      v = w_q[k*192 + c];
        else if (c < 576) v = w_kv[k*384 + (c - 192)];
        else if (c < 720) v = w_qp[k*144 + (c - 576)];
        else              v = w_kvp[k*432 + (c - 720)];
        wcat[idx] = v;
    } else if (idx < 443520) {
        const int c = idx - 442368;
        float v;
        if (c < 192)      v = b_q[c];
        else if (c < 576) v = b_kv[c - 192];
        else if (c < 720) v = b_qp[c - 576];
        else              v = b_kvp[c - 720];
        bcat[c] = v;
    }
}

// ---------------------------------------------------------------- projections GEMM
__global__ __launch_bounds__(256) void k_proj2(
    const float* __restrict__ s, const float* __restrict__ wcat, const float* __restrict__ bcat,
    float* __restrict__ q, float* __restrict__ kkT, float* __restrict__ vcomb,
    float* __restrict__ praw_q, float* __restrict__ praw_kv)
{
    const int ct = blockIdx.x;
    const int n0 = blockIdx.y * 32;
    const int t = threadIdx.x;

    __shared__ float sT[32][34];
    __shared__ float wt[32][36];

    const int lr = t >> 3, lc4 = t & 7;
    const int tr = t >> 4, tc = t & 15;
    float4 sv4, wv4;

    sv4 = *(const float4*)&s[(n0 + lr) * CSD + lc4 * 4];
    wv4 = *(const float4*)&wcat[lr * 1152 + ct * 32 + lc4 * 4];
    sT[lc4*4+0][lr] = sv4.x; sT[lc4*4+1][lr] = sv4.y; sT[lc4*4+2][lr] = sv4.z; sT[lc4*4+3][lr] = sv4.w;
    *(float4*)&wt[lr][lc4*4] = wv4;
    __syncthreads();

    float a00 = 0.f, a01 = 0.f, a10 = 0.f, a11 = 0.f;

    for (int it = 0; it < 12; ++it) {
        if (it < 11) {
            const int k0 = (it + 1) * 32;
            sv4 = *(const float4*)&s[(n0 + lr) * CSD + k0 + lc4 * 4];
            wv4 = *(const float4*)&wcat[(k0 + lr) * 1152 + ct * 32 + lc4 * 4];
        }
        #pragma unroll
        for (int kx = 0; kx < 32; ++kx) {
            float2 ss = *(const float2*)&sT[kx][tr * 2];
            float2 ww = *(const float2*)&wt[kx][tc * 2];
            a00 += ss.x * ww.x; a01 += ss.x * ww.y;
            a10 += ss.y * ww.x; a11 += ss.y * ww.y;
        }
        __syncthreads();
        if (it < 11) {
            sT[lc4*4+0][lr] = sv4.x; sT[lc4*4+1][lr] = sv4.y; sT[lc4*4+2][lr] = sv4.z; sT[lc4*4+3][lr] = sv4.w;
            *(float4*)&wt[lr][lc4*4] = wv4;
            __syncthreads();
        }
    }

    float accv[2][2] = {{a00, a01}, {a10, a11}};
    #pragma unroll
    for (int i = 0; i < 2; ++i) {
        const int n = n0 + tr * 2 + i;
        #pragma unroll
        for (int j = 0; j < 2; ++j) {
            const int gcol = ct * 32 + tc * 2 + j;
            const float v = accv[i][j] + bcat[gcol];
            if (gcol < 192) {
                q[n*192 + gcol] = v;
            } else if (gcol < 576) {
                int g = gcol - 192, h = g >> 5, cc = g & 31;
                if (cc < 16) kkT[(h*16 + cc)*NRES + n] = v;
                else         vcomb[n*NRES + h*16 + (cc-16)] = v;
            } else if (gcol < 720) {
                praw_q[n*144 + (gcol - 576)] = v;
            } else {
                praw_kv[n*432 + (gcol - 720)] = v;
            }
        }
    }
}

// ---------------------------------------------------------------- rigid-frame rotation
__global__ __launch_bounds__(256) void k_rot(
    const float* __restrict__ praw_q, const float* __restrict__ praw_kv,
    const float* __restrict__ rot, const float* __restrict__ trans,
    float* __restrict__ q_pts, float* __restrict__ kptsT, float* __restrict__ vcomb)
{
    const int idx = blockIdx.x * 256 + threadIdx.x;
    const int n = idx / 192, u = idx % 192;
    const float* R = rot + n*9;
    const float* T = trans + n*3;
    float px, py, pz;
    if (u < 48) {
        px = praw_q[n*144 + u]; py = praw_q[n*144 + 48 + u]; pz = praw_q[n*144 + 96 + u];
    } else {
        int pt = u - 48;
        px = praw_kv[n*432 + pt]; py = praw_kv[n*432 + 144 + pt]; pz = praw_kv[n*432 + 288 + pt];
    }
    float x  = R[0]*px + R[1]*py + R[2]*pz + T[0];
    float y  = R[3]*px + R[4]*py + R[5]*pz + T[1];
    float zc = R[6]*px + R[7]*py + R[8]*pz + T[2];
    if (u < 48) {
        int o = (n*48 + u)*3;
        q_pts[o] = x; q_pts[o+1] = y; q_pts[o+2] = zc;
    } else {
        int pt = u - 48;
        int h = pt / 12, pp = pt % 12;
        if (pp < 4) {
            int dim = (h*4 + pp)*3;
            kptsT[(dim+0)*NRES + n] = x;
            kptsT[(dim+1)*NRES + n] = y;
            kptsT[(dim+2)*NRES + n] = zc;
        } else {
            int u2 = (h*8 + (pp-4))*3;
            vcomb[n*NRES + 192 + u2+0] = x;
            vcomb[n*NRES + 192 + u2+1] = y;
            vcomb[n*NRES + 192 + u2+2] = zc;
        }
    }
}

// ---------------------------------------------------------------- fused per-q-row (exact softmax, r6 structure,
// occupancy-optimized: no z LDS staging, LDS union, float2 epi loads). grid 512 x 256thr, ~52KB LDS -> 3 blocks/CU.
__global__ __launch_bounds__(256) void k_row3(
    const float* __restrict__ z,
    const float* __restrict__ q, const float* __restrict__ kkT, const float* __restrict__ vcomb,
    const float* __restrict__ q_pts, const float* __restrict__ kptsT,
    const float* __restrict__ w_b, const float* __restrict__ b_b,
    const float* __restrict__ head_weights, const float* __restrict__ mask,
    const float* __restrict__ rot, const float* __restrict__ trans,
    float* __restrict__ o_cat)
{
    const int qn = blockIdx.x;
    const int t = threadIdx.x;

    __shared__ float U[6144];            // phase1: wb[1536] | part[4][64][13]; phase4: pred[4][12][128]
    __shared__ float a_lds[12][521];
    __shared__ float q_lds[192];
    __shared__ float qp_lds[144];
    __shared__ float hw_lds[12];
    __shared__ float optraw[288];

    float* wb = U;
    float (*part)[64][13] = (float (*)[64][13])&U[1536];

    for (int i = t; i < 1536; i += 256) wb[i] = w_b[i];
    if (t < 192) q_lds[t] = q[qn*192 + t];
    if (t < 144) qp_lds[t] = q_pts[qn*144 + t];
    if (t < 12)  hw_lds[t] = logf(1.f + expf(head_weights[t])) * 0.13608276f;
    __syncthreads();

    const int kx = t & 63, hgrp = t >> 6;

    // ---- phase 1: bias row. z read DIRECT from global (each thread owns a 128B row-segment).
    for (int kt = 0; kt < 8; ++kt) {
        const int k0 = kt*64;
        float4 zr[8];
        const float4* zp = (const float4*)(z + ((size_t)qn*NRES + k0 + kx)*CZD + hgrp*32);
        #pragma unroll
        for (int j = 0; j < 8; ++j) zr[j] = zp[j];
        float acc[12];
        #pragma unroll
        for (int h = 0; h < 12; ++h) acc[h] = 0.f;
        #pragma unroll
        for (int j = 0; j < 8; ++j) {
            const float* wp = &wb[(hgrp*32 + j*4) * 12];
            #pragma unroll
            for (int h = 0; h < 12; ++h) acc[h] += zr[j].x * wp[h];
            #pragma unroll
            for (int h = 0; h < 12; ++h) acc[h] += zr[j].y * wp[12 + h];
            #pragma unroll
            for (int h = 0; h < 12; ++h) acc[h] += zr[j].z * wp[24 + h];
            #pragma unroll
            for (int h = 0; h < 12; ++h) acc[h] += zr[j].w * wp[36 + h];
        }
        #pragma unroll
        for (int h = 0; h < 12; ++h) part[hgrp][kx][h] = acc[h];
        __syncthreads();
        for (int d = t; d < 768; d += 256) {
            int h = d >> 6, k2 = d & 63;
            a_lds[h][k0 + k2] = b_b[h] + part[0][k2][h] + part[1][k2][h]
                              + part[2][k2][h] + part[3][k2][h];
        }
        __syncthreads();
    }

    // ---- phase 2: logits (in-place over a_lds)
    const float mq = mask[qn];
    for (int h = 0; h < 12; ++h) {
        float qv[16], qpv[12];
        #pragma unroll
        for (int c = 0; c < 16; ++c) qv[c] = q_lds[h*16+c];
        #pragma unroll
        for (int d = 0; d < 12; ++d) qpv[d] = qp_lds[h*12+d];
        const float hw = hw_lds[h];
        const float* kT  = kkT + h*16*NRES;
        const float* kpT = kptsT + h*12*NRES;
        #pragma unroll
        for (int r = 0; r < 2; ++r) {
            const int kn = t + r*256;
            float acc = 0.f;
            #pragma unroll
            for (int c = 0; c < 16; ++c) acc += qv[c] * kT[c*NRES + kn];
            acc *= 0.14433757f;
            acc += 0.57735027f * a_lds[h][kn];
            float dsum = 0.f;
            #pragma unroll
            for (int d = 0; d < 12; ++d) { float df = qpv[d] - kpT[d*NRES + kn]; dsum += df*df; }
            a_lds[h][kn] = acc - 0.5f*hw*dsum + (mq*mask[kn]-1.f)*100000.f;
        }
    }
    __syncthreads();

    // ---- phase 3: softmax, warp-parallel across heads (3 heads/wave), normalized in place
    {
        const int w = t >> 6, lane = t & 63;
        for (int h = w; h < 12; h += 4) {
            float m = -1e30f;
            #pragma unroll
            for (int i = 0; i < 8; ++i) m = fmaxf(m, a_lds[h][lane + i*64]);
            #pragma unroll
            for (int off = 32; off > 0; off >>= 1) m = fmaxf(m, __shfl_xor(m, off));
            float ss = 0.f;
            #pragma unroll
            for (int i = 0; i < 8; ++i) {
                float e = __expf(a_lds[h][lane + i*64] - m);
                a_lds[h][lane + i*64] = e;
                ss += e;
            }
            #pragma unroll
            for (int off = 32; off > 0; off >>= 1) ss += __shfl_xor(ss, off);
            float inv = 1.f / ss;
            #pragma unroll
            for (int i = 0; i < 8; ++i) a_lds[h][lane + i*64] *= inv;
        }
    }
    __syncthreads();

    // ---- phase 4: o_pair (z second pass, L3-resident), U re-used as reduce buffer
    {
        const int c4 = t & 31, kgrp = t >> 5;
        const float4* zp = (const float4*)(z + (size_t)qn*NRES*CZD) + c4;
        float4 acc4[12];
        #pragma unroll
        for (int h = 0; h < 12; ++h) acc4[h] = make_float4(0.f,0.f,0.f,0.f);

        #pragma unroll 8
        for (int kn = kgrp; kn < NRES; kn += 8) {
            float4 zv = zp[kn*32];
            #pragma unroll
            for (int h = 0; h < 12; ++h) {
                float av = a_lds[h][kn];
                acc4[h].x += av*zv.x; acc4[h].y += av*zv.y;
                acc4[h].z += av*zv.z; acc4[h].w += av*zv.w;
            }
        }
        #pragma unroll
        for (int h = 0; h < 12; ++h) {
            acc4[h].x += __shfl_xor(acc4[h].x, 32);
            acc4[h].y += __shfl_xor(acc4[h].y, 32);
            acc4[h].z += __shfl_xor(acc4[h].z, 32);
            acc4[h].w += __shfl_xor(acc4[h].w, 32);
        }
        float (*pred)[12][128] = (float (*)[12][128])U;
        const int wave = t >> 6;
        if ((t & 63) < 32) {
            #pragma unroll
            for (int h = 0; h < 12; ++h) {
                pred[wave][h][c4*4+0] = acc4[h].x;
                pred[wave][h][c4*4+1] = acc4[h].y;
                pred[wave][h][c4*4+2] = acc4[h].z;
                pred[wave][h][c4*4+3] = acc4[h].w;
            }
        }
        __syncthreads();
        for (int i = t; i < 1536; i += 256) {
            int h = i >> 7, c = i & 127;
            float v = pred[0][h][c] + pred[1][h][c] + pred[2][h][c] + pred[3][h][c];
            o_cat[qn*2112 + 576 + h*128 + c] = v;
        }
    }

    // ---- phase 5: o (192) + o_pt raw (288) from vcomb (L2), float2 per thread
    if (t < 240) {
        const int ch0 = 2*t, ch1 = 2*t + 1;
        const int hA = (ch0 < 192) ? (ch0 >> 4) : (ch0 - 192) / 24;
        const int hB = (ch1 < 192) ? (ch1 >> 4) : (ch1 - 192) / 24;
        float aAcc = 0.f, bAcc = 0.f;
        const float2* vp2 = (const float2*)vcomb + t;
        #pragma unroll 8
        for (int kn = 0; kn < NRES; ++kn) {
            float2 v = vp2[(size_t)kn*256];
            aAcc += a_lds[hA][kn] * v.x;
            bAcc += a_lds[hB][kn] * v.y;
        }
        if (ch0 < 192) o_cat[qn*2112 + ch0] = aAcc;
        else           optraw[ch0 - 192] = aAcc;
        if (ch1 < 192) o_cat[qn*2112 + ch1] = bAcc;
        else           optraw[ch1 - 192] = bAcc;
    }
    __syncthreads();

    // ---- phase 6: inverse rotation + norms
    if (t < 96) {
        const float* R = rot + qn*9;
        const float* T = trans + qn*3;
        float ox = optraw[t*3]   - T[0];
        float oy = optraw[t*3+1] - T[1];
        float oz = optraw[t*3+2] - T[2];
        float x  = R[0]*ox + R[3]*oy + R[6]*oz;
        float y  = R[1]*ox + R[4]*oy + R[7]*oz;
        float zc = R[2]*ox + R[5]*oy + R[8]*oz;
        float* ob = o_cat + qn*2112;
        ob[192 + t] = x;
        ob[288 + t] = y;
        ob[384 + t] = zc;
        ob[480 + t] = sqrtf(x*x + y*y + zc*zc + 1e-8f);
    }
}

// ---------------------------------------------------------------- final GEMM
__global__ __launch_bounds__(256) void k_out2(
    const float* __restrict__ o_cat, const float* __restrict__ w_out, float* __restrict__ part)
{
    const int ct = blockIdx.x;
    const int n0 = blockIdx.y * 32;
    const int kc = blockIdx.z;
    const int t = threadIdx.x;

    __shared__ float oT[32][34];
    __shared__ float wt[32][36];

    const int lr = t >> 3, lc4 = t & 7;
    const int tr = t >> 4, tc = t & 15;
    const int kbase = kc * 352;
    float4 ov4, wv4;

    ov4 = *(const float4*)&o_cat[(n0 + lr) * 2112 + kbase + lc4 * 4];
    wv4 = *(const float4*)&w_out[(kbase + lr) * 384 + ct * 32 + lc4 * 4];
    oT[lc4*4+0][lr] = ov4.x; oT[lc4*4+1][lr] = ov4.y; oT[lc4*4+2][lr] = ov4.z; oT[lc4*4+3][lr] = ov4.w;
    *(float4*)&wt[lr][lc4*4] = wv4;
    __syncthreads();

    float a00 = 0.f, a01 = 0.f, a10 = 0.f, a11 = 0.f;

    for (int it = 0; it < 11; ++it) {
        if (it < 10) {
            const int k0 = kbase + (it + 1) * 32;
            ov4 = *(const float4*)&o_cat[(n0 + lr) * 2112 + k0 + lc4 * 4];
            wv4 = *(const float4*)&w_out[(k0 + lr) * 384 + ct * 32 + lc4 * 4];
        }
        #pragma unroll
        for (int kx = 0; kx < 32; ++kx) {
            float2 oo = *(const float2*)&oT[kx][tr * 2];
            float2 ww = *(const float2*)&wt[kx][tc * 2];
            a00 += oo.x * ww.x; a01 += oo.x * ww.y;
            a10 += oo.y * ww.x; a11 += oo.y * ww.y;
        }
        __syncthreads();
        if (it < 10) {
            oT[lc4*4+0][lr] = ov4.x; oT[lc4*4+1][lr] = ov4.y; oT[lc4*4+2][lr] = ov4.z; oT[lc4*4+3][lr] = ov4.w;
            *(float4*)&wt[lr][lc4*4] = wv4;
            __syncthreads();
        }
    }

    float* pp = part + (size_t)kc * 196608;
    pp[(n0 + tr*2 + 0)*384 + ct*32 + tc*2 + 0] = a00;
    pp[(n0 + tr*2 + 0)*384 + ct*32 + tc*2 + 1] = a01;
    pp[(n0 + tr*2 + 1)*384 + ct*32 + tc*2 + 0] = a10;
    pp[(n0 + tr*2 + 1)*384 + ct*32 + tc*2 + 1] = a11;
}

__global__ __launch_bounds__(256) void k_red(
    const float* __restrict__ part, const float* __restrict__ b_out, float* __restrict__ out)
{
    const int i = blockIdx.x*256 + threadIdx.x;
    float acc = b_out[i % 384];
    #pragma unroll
    for (int dc = 0; dc < 6; ++dc) acc += part[(size_t)dc*196608 + i];
    out[i] = acc;
}

// ----------------------------------------------------------------
extern "C" void kernel_launch(void* const* d_in, const int* in_sizes, int n_in,
                              void* d_out, int out_size, void* d_ws, size_t ws_size,
                              hipStream_t stream) {
    (void)in_sizes; (void)n_in; (void)out_size; (void)ws_size;
    const float* s      = (const float*)d_in[0];
    const float* z      = (const float*)d_in[1];
    const float* rot    = (const float*)d_in[2];
    const float* trans  = (const float*)d_in[3];
    const float* mask   = (const float*)d_in[4];
    const float* w_q    = (const float*)d_in[5];
    const float* b_q    = (const float*)d_in[6];
    const float* w_kv   = (const float*)d_in[7];
    const float* b_kv   = (const float*)d_in[8];
    const float* w_qp   = (const float*)d_in[9];
    const float* b_qp   = (const float*)d_in[10];
    const float* w_kvp  = (const float*)d_in[11];
    const float* b_kvp  = (const float*)d_in[12];
    const float* w_b    = (const float*)d_in[13];
    const float* b_b    = (const float*)d_in[14];
    const float* hwts   = (const float*)d_in[15];
    const float* w_out  = (const float*)d_in[16];
    const float* b_out  = (const float*)d_in[17];
    float* out = (float*)d_out;
    float* ws  = (float*)d_ws;

    float* q      = ws + OFF_Q;
    float* kkT    = ws + OFF_KT;
    float* vcomb  = ws + OFF_VC;
    float* qp     = ws + OFF_QP;
    float* kptsT  = ws + OFF_KPT;
    float* ocat   = ws + OFF_OCAT;
    float* wcat   = ws + OFF_WCAT;
    float* bcat   = ws + OFF_BCAT;
    float* part   = ws + OFF_PART;
    float* praw_q  = ws + OFF_PRAWQ;
    float* praw_kv = ws + OFF_PRAWK;

    k_wcat<<<dim3(1733), dim3(256), 0, stream>>>(w_q, b_q, w_kv, b_kv, w_qp, b_qp, w_kvp, b_kvp, wcat, bcat);
    k_proj2<<<dim3(36, 16), dim3(256), 0, stream>>>(s, wcat, bcat, q, kkT, vcomb, praw_q, praw_kv);
    k_rot<<<dim3(384), dim3(256), 0, stream>>>(praw_q, praw_kv, rot, trans, qp, kptsT, vcomb);
    k_row3<<<dim3(NRES), dim3(256), 0, stream>>>(z, q, kkT, vcomb, qp, kptsT,
        w_b, b_b, hwts, mask, rot, trans, ocat);
    k_out2<<<dim3(12, 16, 6), dim3(256), 0, stream>>>(ocat, w_out, part);
    k_red<<<dim3(768), dim3(256), 0, stream>>>(part, b_out, out);
}

// Round 9
// 180.178 us; speedup vs baseline: 2.5799x; 1.3058x over previous
//
#include <hip/hip_runtime.h>
#include <math.h>

#define NRES 512
#define CSD  384
#define CZD  128

// workspace layout (float offsets)
#define OFF_Q     0         //  512*192
#define OFF_KT    98304     //  192*512   kkT[c][k]
#define OFF_VC    196608    //  512*512   vcomb[k][u]  (u<192: v, 192..479: v_pts)
#define OFF_QP    458752    //  512*144   q_pts row-major
#define OFF_KPT   532480    //  144*512   kptsT[dim][k]
#define OFF_A     606208    //  3145728: biasT[h][q][k] (k_bias2->k_row4), then part (k_out2->k_red)
#define OFF_OCAT  3751936   //  512*2112
#define OFF_WCAT  4833280   //  384*1152 wcat + 1152 bcat
#define OFF_BCAT  (OFF_WCAT + 442368)
#define OFF_PRAWQ 5276800   //  512*144 (k_proj2 -> k_rot)
#define OFF_PRAWK 5350528   //  512*432
#define OFF_PART  OFF_A     //  6*196608 (k_out2 -> k_red, biasT dead by then)

// ---------------------------------------------------------------- weight concat
__global__ __launch_bounds__(256) void k_wcat(
    const float* __restrict__ w_q, const float* __restrict__ b_q,
    const float* __restrict__ w_kv, const float* __restrict__ b_kv,
    const float* __restrict__ w_qp, const float* __restrict__ b_qp,
    const float* __restrict__ w_kvp, const float* __restrict__ b_kvp,
    float* __restrict__ wcat, float* __restrict__ bcat)
{
    const int idx = blockIdx.x * 256 + threadIdx.x;
    if (idx < 442368) {
        const int k = idx / 1152, c = idx % 1152;
        float v;
        if (c < 192)      v = w_q[k*192 + c];
        else if (c < 576) v = w_kv[k*384 + (c - 192)];
        else if (c < 720) v = w_qp[k*144 + (c - 576)];
        else              v = w_kvp[k*432 + (c - 720)];
        wcat[idx] = v;
    } else if (idx < 443520) {
        const int c = idx - 442368;
        float v;
        if (c < 192)      v = b_q[c];
        else if (c < 576) v = b_kv[c - 192];
        else if (c < 720) v = b_qp[c - 576];
        else              v = b_kvp[c - 720];
        bcat[c] = v;
    }
}

// ---------------------------------------------------------------- projections GEMM
__global__ __launch_bounds__(256) void k_proj2(
    const float* __restrict__ s, const float* __restrict__ wcat, const float* __restrict__ bcat,
    float* __restrict__ q, float* __restrict__ kkT, float* __restrict__ vcomb,
    float* __restrict__ praw_q, float* __restrict__ praw_kv)
{
    const int ct = blockIdx.x;
    const int n0 = blockIdx.y * 32;
    const int t = threadIdx.x;

    __shared__ float sT[32][34];
    __shared__ float wt[32][36];

    const int lr = t >> 3, lc4 = t & 7;
    const int tr = t >> 4, tc = t & 15;
    float4 sv4, wv4;

    sv4 = *(const float4*)&s[(n0 + lr) * CSD + lc4 * 4];
    wv4 = *(const float4*)&wcat[lr * 1152 + ct * 32 + lc4 * 4];
    sT[lc4*4+0][lr] = sv4.x; sT[lc4*4+1][lr] = sv4.y; sT[lc4*4+2][lr] = sv4.z; sT[lc4*4+3][lr] = sv4.w;
    *(float4*)&wt[lr][lc4*4] = wv4;
    __syncthreads();

    float a00 = 0.f, a01 = 0.f, a10 = 0.f, a11 = 0.f;

    for (int it = 0; it < 12; ++it) {
        if (it < 11) {
            const int k0 = (it + 1) * 32;
            sv4 = *(const float4*)&s[(n0 + lr) * CSD + k0 + lc4 * 4];
            wv4 = *(const float4*)&wcat[(k0 + lr) * 1152 + ct * 32 + lc4 * 4];
        }
        #pragma unroll
        for (int kx = 0; kx < 32; ++kx) {
            float2 ss = *(const float2*)&sT[kx][tr * 2];
            float2 ww = *(const float2*)&wt[kx][tc * 2];
            a00 += ss.x * ww.x; a01 += ss.x * ww.y;
            a10 += ss.y * ww.x; a11 += ss.y * ww.y;
        }
        __syncthreads();
        if (it < 11) {
            sT[lc4*4+0][lr] = sv4.x; sT[lc4*4+1][lr] = sv4.y; sT[lc4*4+2][lr] = sv4.z; sT[lc4*4+3][lr] = sv4.w;
            *(float4*)&wt[lr][lc4*4] = wv4;
            __syncthreads();
        }
    }

    float accv[2][2] = {{a00, a01}, {a10, a11}};
    #pragma unroll
    for (int i = 0; i < 2; ++i) {
        const int n = n0 + tr * 2 + i;
        #pragma unroll
        for (int j = 0; j < 2; ++j) {
            const int gcol = ct * 32 + tc * 2 + j;
            const float v = accv[i][j] + bcat[gcol];
            if (gcol < 192) {
                q[n*192 + gcol] = v;
            } else if (gcol < 576) {
                int g = gcol - 192, h = g >> 5, cc = g & 31;
                if (cc < 16) kkT[(h*16 + cc)*NRES + n] = v;
                else         vcomb[n*NRES + h*16 + (cc-16)] = v;
            } else if (gcol < 720) {
                praw_q[n*144 + (gcol - 576)] = v;
            } else {
                praw_kv[n*432 + (gcol - 720)] = v;
            }
        }
    }
}

// ---------------------------------------------------------------- rigid-frame rotation
__global__ __launch_bounds__(256) void k_rot(
    const float* __restrict__ praw_q, const float* __restrict__ praw_kv,
    const float* __restrict__ rot, const float* __restrict__ trans,
    float* __restrict__ q_pts, float* __restrict__ kptsT, float* __restrict__ vcomb)
{
    const int idx = blockIdx.x * 256 + threadIdx.x;
    const int n = idx / 192, u = idx % 192;
    const float* R = rot + n*9;
    const float* T = trans + n*3;
    float px, py, pz;
    if (u < 48) {
        px = praw_q[n*144 + u]; py = praw_q[n*144 + 48 + u]; pz = praw_q[n*144 + 96 + u];
    } else {
        int pt = u - 48;
        px = praw_kv[n*432 + pt]; py = praw_kv[n*432 + 144 + pt]; pz = praw_kv[n*432 + 288 + pt];
    }
    float x  = R[0]*px + R[1]*py + R[2]*pz + T[0];
    float y  = R[3]*px + R[4]*py + R[5]*pz + T[1];
    float zc = R[6]*px + R[7]*py + R[8]*pz + T[2];
    if (u < 48) {
        int o = (n*48 + u)*3;
        q_pts[o] = x; q_pts[o+1] = y; q_pts[o+2] = zc;
    } else {
        int pt = u - 48;
        int h = pt / 12, pp = pt % 12;
        if (pp < 4) {
            int dim = (h*4 + pp)*3;
            kptsT[(dim+0)*NRES + n] = x;
            kptsT[(dim+1)*NRES + n] = y;
            kptsT[(dim+2)*NRES + n] = zc;
        } else {
            int u2 = (h*8 + (pp-4))*3;
            vcomb[n*NRES + 192 + u2+0] = x;
            vcomb[n*NRES + 192 + u2+1] = y;
            vcomb[n*NRES + 192 + u2+2] = zc;
        }
    }
}

// ---------------------------------------------------------------- biasT[h][q][k] = z @ w_b + b_b
// grid (8, 512) = 4096 blocks, staged-coalesced z tiles, no cross-wave reduce.
__global__ __launch_bounds__(256) void k_bias2(
    const float* __restrict__ z, const float* __restrict__ w_b, const float* __restrict__ b_b,
    float* __restrict__ biasT)
{
    const int qn = blockIdx.y;
    const int k0 = blockIdx.x * 64;
    const int t = threadIdx.x;
    __shared__ float zt[64*129];
    __shared__ float wb[1536];

    for (int i = t; i < 1536; i += 256) wb[i] = w_b[i];
    const float4* zp4 = (const float4*)(z + ((size_t)qn*NRES + k0)*CZD);
    #pragma unroll
    for (int r = 0; r < 8; ++r) {
        int idx = t + r*256;
        int kx = idx >> 5, c4 = idx & 31;
        float4 v4 = zp4[idx];
        float* dst = &zt[kx*129 + c4*4];
        dst[0] = v4.x; dst[1] = v4.y; dst[2] = v4.z; dst[3] = v4.w;
    }
    __syncthreads();

    const int k = t & 63;
    const int h0 = (t >> 6) * 3;          // wave w owns heads 3w..3w+2 (wb reads broadcast)
    float acc0 = b_b[h0], acc1 = b_b[h0+1], acc2 = b_b[h0+2];
    const float* zrow = &zt[k*129];
    #pragma unroll 4
    for (int c = 0; c < 128; ++c) {
        float zv = zrow[c];
        const float* wp = &wb[c*12 + h0];
        acc0 += zv * wp[0];
        acc1 += zv * wp[1];
        acc2 += zv * wp[2];
    }
    const size_t base = (size_t)qn*NRES + k0 + k;
    biasT[(size_t)(h0+0)*NRES*NRES + base] = acc0;
    biasT[(size_t)(h0+1)*NRES*NRES + base] = acc1;
    biasT[(size_t)(h0+2)*NRES*NRES + base] = acc2;
}

// ---------------------------------------------------------------- fused per-q-row: logits+softmax+o_pair+o/o_pt+rot
// bias precomputed; ~52KB LDS -> 3 blocks/CU.
__global__ __launch_bounds__(256, 3) void k_row4(
    const float* __restrict__ z, const float* __restrict__ biasT,
    const float* __restrict__ q, const float* __restrict__ kkT, const float* __restrict__ vcomb,
    const float* __restrict__ q_pts, const float* __restrict__ kptsT,
    const float* __restrict__ head_weights, const float* __restrict__ mask,
    const float* __restrict__ rot, const float* __restrict__ trans,
    float* __restrict__ o_cat)
{
    const int qn = blockIdx.x;
    const int t = threadIdx.x;

    __shared__ float a_lds[12][521];
    __shared__ float pred[4][12][128];
    __shared__ float q_lds[192];
    __shared__ float qp_lds[144];
    __shared__ float hw_lds[12];
    __shared__ float optraw[288];

    if (t < 192) q_lds[t] = q[qn*192 + t];
    if (t < 144) qp_lds[t] = q_pts[qn*144 + t];
    if (t < 12)  hw_lds[t] = logf(1.f + expf(head_weights[t])) * 0.13608276f;
    __syncthreads();

    // ---- phase 2: logits (bias read from global biasT, coalesced)
    const float mq = mask[qn];
    for (int h = 0; h < 12; ++h) {
        float qv[16], qpv[12];
        #pragma unroll
        for (int c = 0; c < 16; ++c) qv[c] = q_lds[h*16+c];
        #pragma unroll
        for (int d = 0; d < 12; ++d) qpv[d] = qp_lds[h*12+d];
        const float hw = hw_lds[h];
        const float* kT  = kkT + h*16*NRES;
        const float* kpT = kptsT + h*12*NRES;
        const float* brow = biasT + (size_t)h*NRES*NRES + (size_t)qn*NRES;
        #pragma unroll
        for (int r = 0; r < 2; ++r) {
            const int kn = t + r*256;
            float acc = 0.f;
            #pragma unroll
            for (int c = 0; c < 16; ++c) acc += qv[c] * kT[c*NRES + kn];
            acc *= 0.14433757f;
            acc += 0.57735027f * brow[kn];
            float dsum = 0.f;
            #pragma unroll
            for (int d = 0; d < 12; ++d) { float df = qpv[d] - kpT[d*NRES + kn]; dsum += df*df; }
            a_lds[h][kn] = acc - 0.5f*hw*dsum + (mq*mask[kn]-1.f)*100000.f;
        }
    }
    __syncthreads();

    // ---- phase 3: softmax, warp-parallel across heads (3 heads/wave), normalized in place
    {
        const int w = t >> 6, lane = t & 63;
        for (int h = w; h < 12; h += 4) {
            float m = -1e30f;
            #pragma unroll
            for (int i = 0; i < 8; ++i) m = fmaxf(m, a_lds[h][lane + i*64]);
            #pragma unroll
            for (int off = 32; off > 0; off >>= 1) m = fmaxf(m, __shfl_xor(m, off));
            float ss = 0.f;
            #pragma unroll
            for (int i = 0; i < 8; ++i) {
                float e = __expf(a_lds[h][lane + i*64] - m);
                a_lds[h][lane + i*64] = e;
                ss += e;
            }
            #pragma unroll
            for (int off = 32; off > 0; off >>= 1) ss += __shfl_xor(ss, off);
            float inv = 1.f / ss;
            #pragma unroll
            for (int i = 0; i < 8; ++i) a_lds[h][lane + i*64] *= inv;
        }
    }
    __syncthreads();

    // ---- phase 4: o_pair (z second pass, L3-resident)
    {
        const int c4 = t & 31, kgrp = t >> 5;
        const float4* zp = (const float4*)(z + (size_t)qn*NRES*CZD) + c4;
        float4 acc4[12];
        #pragma unroll
        for (int h = 0; h < 12; ++h) acc4[h] = make_float4(0.f,0.f,0.f,0.f);

        #pragma unroll 8
        for (int kn = kgrp; kn < NRES; kn += 8) {
            float4 zv = zp[kn*32];
            #pragma unroll
            for (int h = 0; h < 12; ++h) {
                float av = a_lds[h][kn];
                acc4[h].x += av*zv.x; acc4[h].y += av*zv.y;
                acc4[h].z += av*zv.z; acc4[h].w += av*zv.w;
            }
        }
        #pragma unroll
        for (int h = 0; h < 12; ++h) {
            acc4[h].x += __shfl_xor(acc4[h].x, 32);
            acc4[h].y += __shfl_xor(acc4[h].y, 32);
            acc4[h].z += __shfl_xor(acc4[h].z, 32);
            acc4[h].w += __shfl_xor(acc4[h].w, 32);
        }
        const int wave = t >> 6;
        if ((t & 63) < 32) {
            #pragma unroll
            for (int h = 0; h < 12; ++h) {
                pred[wave][h][c4*4+0] = acc4[h].x;
                pred[wave][h][c4*4+1] = acc4[h].y;
                pred[wave][h][c4*4+2] = acc4[h].z;
                pred[wave][h][c4*4+3] = acc4[h].w;
            }
        }
        __syncthreads();
        for (int i = t; i < 1536; i += 256) {
            int h = i >> 7, c = i & 127;
            float v = pred[0][h][c] + pred[1][h][c] + pred[2][h][c] + pred[3][h][c];
            o_cat[qn*2112 + 576 + h*128 + c] = v;
        }
    }

    // ---- phase 5: o (192) + o_pt raw (288) from vcomb (L2), float2 per thread
    if (t < 240) {
        const int ch0 = 2*t, ch1 = 2*t + 1;
        const int hA = (ch0 < 192) ? (ch0 >> 4) : (ch0 - 192) / 24;
        const int hB = (ch1 < 192) ? (ch1 >> 4) : (ch1 - 192) / 24;
        float aAcc = 0.f, bAcc = 0.f;
        const float2* vp2 = (const float2*)vcomb + t;
        #pragma unroll 8
        for (int kn = 0; kn < NRES; ++kn) {
            float2 v = vp2[(size_t)kn*256];
            aAcc += a_lds[hA][kn] * v.x;
            bAcc += a_lds[hB][kn] * v.y;
        }
        if (ch0 < 192) o_cat[qn*2112 + ch0] = aAcc;
        else           optraw[ch0 - 192] = aAcc;
        if (ch1 < 192) o_cat[qn*2112 + ch1] = bAcc;
        else           optraw[ch1 - 192] = bAcc;
    }
    __syncthreads();

    // ---- phase 6: inverse rotation + norms
    if (t < 96) {
        const float* R = rot + qn*9;
        const float* T = trans + qn*3;
        float ox = optraw[t*3]   - T[0];
        float oy = optraw[t*3+1] - T[1];
        float oz = optraw[t*3+2] - T[2];
        float x  = R[0]*ox + R[3]*oy + R[6]*oz;
        float y  = R[1]*ox + R[4]*oy + R[7]*oz;
        float zc = R[2]*ox + R[5]*oy + R[8]*oz;
        float* ob = o_cat + qn*2112;
        ob[192 + t] = x;
        ob[288 + t] = y;
        ob[384 + t] = zc;
        ob[480 + t] = sqrtf(x*x + y*y + zc*zc + 1e-8f);
    }
}

// ---------------------------------------------------------------- final GEMM
__global__ __launch_bounds__(256) void k_out2(
    const float* __restrict__ o_cat, const float* __restrict__ w_out, float* __restrict__ part)
{
    const int ct = blockIdx.x;
    const int n0 = blockIdx.y * 32;
    const int kc = blockIdx.z;
    const int t = threadIdx.x;

    __shared__ float oT[32][34];
    __shared__ float wt[32][36];

    const int lr = t >> 3, lc4 = t & 7;
    const int tr = t >> 4, tc = t & 15;
    const int kbase = kc * 352;
    float4 ov4, wv4;

    ov4 = *(const float4*)&o_cat[(n0 + lr) * 2112 + kbase + lc4 * 4];
    wv4 = *(const float4*)&w_out[(kbase + lr) * 384 + ct * 32 + lc4 * 4];
    oT[lc4*4+0][lr] = ov4.x; oT[lc4*4+1][lr] = ov4.y; oT[lc4*4+2][lr] = ov4.z; oT[lc4*4+3][lr] = ov4.w;
    *(float4*)&wt[lr][lc4*4] = wv4;
    __syncthreads();

    float a00 = 0.f, a01 = 0.f, a10 = 0.f, a11 = 0.f;

    for (int it = 0; it < 11; ++it) {
        if (it < 10) {
            const int k0 = kbase + (it + 1) * 32;
            ov4 = *(const float4*)&o_cat[(n0 + lr) * 2112 + k0 + lc4 * 4];
            wv4 = *(const float4*)&w_out[(k0 + lr) * 384 + ct * 32 + lc4 * 4];
        }
        #pragma unroll
        for (int kx = 0; kx < 32; ++kx) {
            float2 oo = *(const float2*)&oT[kx][tr * 2];
            float2 ww = *(const float2*)&wt[kx][tc * 2];
            a00 += oo.x * ww.x; a01 += oo.x * ww.y;
            a10 += oo.y * ww.x; a11 += oo.y * ww.y;
        }
        __syncthreads();
        if (it < 10) {
            oT[lc4*4+0][lr] = ov4.x; oT[lc4*4+1][lr] = ov4.y; oT[lc4*4+2][lr] = ov4.z; oT[lc4*4+3][lr] = ov4.w;
            *(float4*)&wt[lr][lc4*4] = wv4;
            __syncthreads();
        }
    }

    float* pp = part + (size_t)kc * 196608;
    pp[(n0 + tr*2 + 0)*384 + ct*32 + tc*2 + 0] = a00;
    pp[(n0 + tr*2 + 0)*384 + ct*32 + tc*2 + 1] = a01;
    pp[(n0 + tr*2 + 1)*384 + ct*32 + tc*2 + 0] = a10;
    pp[(n0 + tr*2 + 1)*384 + ct*32 + tc*2 + 1] = a11;
}

__global__ __launch_bounds__(256) void k_red(
    const float* __restrict__ part, const float* __restrict__ b_out, float* __restrict__ out)
{
    const int i = blockIdx.x*256 + threadIdx.x;
    float acc = b_out[i % 384];
    #pragma unroll
    for (int dc = 0; dc < 6; ++dc) acc += part[(size_t)dc*196608 + i];
    out[i] = acc;
}

// ----------------------------------------------------------------
extern "C" void kernel_launch(void* const* d_in, const int* in_sizes, int n_in,
                              void* d_out, int out_size, void* d_ws, size_t ws_size,
                              hipStream_t stream) {
    (void)in_sizes; (void)n_in; (void)out_size; (void)ws_size;
    const float* s      = (const float*)d_in[0];
    const float* z      = (const float*)d_in[1];
    const float* rot    = (const float*)d_in[2];
    const float* trans  = (const float*)d_in[3];
    const float* mask   = (const float*)d_in[4];
    const float* w_q    = (const float*)d_in[5];
    const float* b_q    = (const float*)d_in[6];
    const float* w_kv   = (const float*)d_in[7];
    const float* b_kv   = (const float*)d_in[8];
    const float* w_qp   = (const float*)d_in[9];
    const float* b_qp   = (const float*)d_in[10];
    const float* w_kvp  = (const float*)d_in[11];
    const float* b_kvp  = (const float*)d_in[12];
    const float* w_b    = (const float*)d_in[13];
    const float* b_b    = (const float*)d_in[14];
    const float* hwts   = (const float*)d_in[15];
    const float* w_out  = (const float*)d_in[16];
    const float* b_out  = (const float*)d_in[17];
    float* out = (float*)d_out;
    float* ws  = (float*)d_ws;

    float* q      = ws + OFF_Q;
    float* kkT    = ws + OFF_KT;
    float* vcomb  = ws + OFF_VC;
    float* qp     = ws + OFF_QP;
    float* kptsT  = ws + OFF_KPT;
    float* biasT  = ws + OFF_A;
    float* ocat   = ws + OFF_OCAT;
    float* wcat   = ws + OFF_WCAT;
    float* bcat   = ws + OFF_BCAT;
    float* part   = ws + OFF_PART;
    float* praw_q  = ws + OFF_PRAWQ;
    float* praw_kv = ws + OFF_PRAWK;

    k_bias2<<<dim3(8, NRES), dim3(256), 0, stream>>>(z, w_b, b_b, biasT);
    k_wcat<<<dim3(1733), dim3(256), 0, stream>>>(w_q, b_q, w_kv, b_kv, w_qp, b_qp, w_kvp, b_kvp, wcat, bcat);
    k_proj2<<<dim3(36, 16), dim3(256), 0, stream>>>(s, wcat, bcat, q, kkT, vcomb, praw_q, praw_kv);
    k_rot<<<dim3(384), dim3(256), 0, stream>>>(praw_q, praw_kv, rot, trans, qp, kptsT, vcomb);
    k_row4<<<dim3(NRES), dim3(256), 0, stream>>>(z, biasT, q, kkT, vcomb, qp, kptsT,
        hwts, mask, rot, trans, ocat);
    k_out2<<<dim3(12, 16, 6), dim3(256), 0, stream>>>(ocat, w_out, part);
    k_red<<<dim3(768), dim3(256), 0, stream>>>(part, b_out, out);
}